// Round 1
// baseline (346.326 us; speedup 1.0000x reference)
//
#include <hip/hip_runtime.h>
#include <math.h>
#include <stdint.h>

typedef unsigned int u32;
typedef unsigned long long u64;

#define BLOCK 256
#define ITEMS 16
#define CHUNK (BLOCK * ITEMS)  // 4096 elements per block

// ---------------------------------------------------------------------------
// Pass 1: per-block class histograms (4 classes).
// ---------------------------------------------------------------------------
__global__ void hist_kernel(const int* __restrict__ labels, int N,
                            u32* __restrict__ hist) {
    __shared__ u32 h[4];
    int tid = threadIdx.x;
    if (tid < 4) h[tid] = 0;
    __syncthreads();
    int base = blockIdx.x * CHUNK;
    u32 c0 = 0, c1 = 0, c2 = 0, c3 = 0;
#pragma unroll
    for (int j = 0; j < ITEMS; ++j) {
        int idx = base + j * BLOCK + tid;
        if (idx < N) {
            int l = labels[idx];
            c0 += (l == 0); c1 += (l == 1); c2 += (l == 2); c3 += (l == 3);
        }
    }
    atomicAdd(&h[0], c0);
    atomicAdd(&h[1], c1);
    atomicAdd(&h[2], c2);
    atomicAdd(&h[3], c3);
    __syncthreads();
    if (tid < 4) hist[blockIdx.x * 4 + tid] = h[tid];
}

// ---------------------------------------------------------------------------
// Pass 2 (single block): scan block histograms -> per-block scatter bases
// (already including class base), class bases, zero loss accumulator.
// ---------------------------------------------------------------------------
__global__ void scan_kernel(const u32* __restrict__ hist,
                            u32* __restrict__ boff,
                            u32* __restrict__ cbase,
                            double* __restrict__ acc,
                            int nb) {
    __shared__ uint4 s[BLOCK];
    __shared__ u32 sb[4];
    int t = threadIdx.x;
    int m = (nb + BLOCK - 1) / BLOCK;
    int b0 = t * m;
    int b1 = min(b0 + m, nb);
    uint4 loc = make_uint4(0, 0, 0, 0);
    for (int b = b0; b < b1; ++b) {
        loc.x += hist[b * 4 + 0];
        loc.y += hist[b * 4 + 1];
        loc.z += hist[b * 4 + 2];
        loc.w += hist[b * 4 + 3];
    }
    s[t] = loc;
    __syncthreads();
    // Hillis-Steele inclusive scan over 256 uint4
    for (int off = 1; off < BLOCK; off <<= 1) {
        uint4 v = make_uint4(0, 0, 0, 0);
        if (t >= off) v = s[t - off];
        __syncthreads();
        s[t].x += v.x; s[t].y += v.y; s[t].z += v.z; s[t].w += v.w;
        __syncthreads();
    }
    uint4 inc = s[t];
    uint4 tot = s[BLOCK - 1];
    if (t == 0) {
        sb[0] = 0;
        sb[1] = tot.x;
        sb[2] = tot.x + tot.y;
        sb[3] = tot.x + tot.y + tot.z;
        cbase[0] = sb[0]; cbase[1] = sb[1]; cbase[2] = sb[2]; cbase[3] = sb[3];
        *acc = 0.0;
    }
    __syncthreads();
    uint4 run;
    run.x = inc.x - loc.x + sb[0];
    run.y = inc.y - loc.y + sb[1];
    run.z = inc.z - loc.z + sb[2];
    run.w = inc.w - loc.w + sb[3];
    for (int b = b0; b < b1; ++b) {
        boff[b * 4 + 0] = run.x;
        boff[b * 4 + 1] = run.y;
        boff[b * 4 + 2] = run.z;
        boff[b * 4 + 3] = run.w;
        run.x += hist[b * 4 + 0];
        run.y += hist[b * 4 + 1];
        run.z += hist[b * 4 + 2];
        run.w += hist[b * 4 + 3];
    }
}

// ---------------------------------------------------------------------------
// Pass 3: stable rank + margin adjust + scatter + loss accumulation.
// ---------------------------------------------------------------------------
__global__ void scatter_kernel(const float4* __restrict__ data,
                               const int* __restrict__ labels, int N,
                               const u32* __restrict__ boff,
                               float4* __restrict__ out_data,
                               double* __restrict__ acc) {
    __shared__ u32 s_cnt[2][4][4];  // [buf][wave][class]
    __shared__ u32 s_run[4];
    __shared__ u32 s_b[4];
    __shared__ double s_w[4];
    int tid = threadIdx.x;
    if (tid < 4) {
        s_run[tid] = 0;
        s_b[tid] = boff[blockIdx.x * 4 + tid];
    }
    __syncthreads();
    int base = blockIdx.x * CHUNK;
    int lane = tid & 63;
    int wave = tid >> 6;
    u64 ltm = (1ULL << lane) - 1ULL;
    float loss = 0.f;
    for (int j = 0; j < ITEMS; ++j) {
        int p = j & 1;
        int idx = base + j * BLOCK + tid;
        bool valid = idx < N;
        int l = valid ? labels[idx] : -1;
        u64 m0 = __ballot(l == 0);
        u64 m1 = __ballot(l == 1);
        u64 m2 = __ballot(l == 2);
        u64 m3 = __ballot(l == 3);
        if (lane == 0) {
            s_cnt[p][wave][0] = (u32)__popcll(m0);
            s_cnt[p][wave][1] = (u32)__popcll(m1);
            s_cnt[p][wave][2] = (u32)__popcll(m2);
            s_cnt[p][wave][3] = (u32)__popcll(m3);
        }
        __syncthreads();
        if (valid) {
            u64 mm = (l == 0) ? m0 : (l == 1) ? m1 : (l == 2) ? m2 : m3;
            u32 pre = (u32)__popcll(mm & ltm);
            u32 wb = 0;
#pragma unroll
            for (int w = 0; w < 3; ++w)
                if (w < wave) wb += s_cnt[p][w][l];
            u32 dst = s_b[l] + s_run[l] + wb + pre;
            float4 r = data[idx];
            float v = (l == 0) ? r.x : (l == 1) ? r.y : (l == 2) ? r.z : r.w;
            float adj = (v > 0.f) ? (v / 4.00001f - 0.5f) : (v * 4.00001f - 0.5f);
            if (l == 0) r.x = adj;
            else if (l == 1) r.y = adj;
            else if (l == 2) r.z = adj;
            else r.w = adj;
            out_data[dst] = r;
            float mx = fmaxf(fmaxf(r.x, r.y), fmaxf(r.z, r.w));
            float se = expf(r.x - mx) + expf(r.y - mx) + expf(r.z - mx) + expf(r.w - mx);
            loss += (mx + logf(se)) - adj;  // -log p_true
        }
        __syncthreads();
        if (tid < 4)
            s_run[tid] += s_cnt[p][0][tid] + s_cnt[p][1][tid] +
                          s_cnt[p][2][tid] + s_cnt[p][3][tid];
        // visibility of s_run update is guaranteed by next iteration's first
        // __syncthreads(); s_cnt double-buffering removes the write race.
    }
    // block-reduce loss in double
    double d = (double)loss;
#pragma unroll
    for (int off = 32; off > 0; off >>= 1) d += __shfl_down(d, off, 64);
    if (lane == 0) s_w[wave] = d;
    __syncthreads();
    if (tid == 0) {
        atomicAdd(acc, s_w[0] + s_w[1] + s_w[2] + s_w[3]);
    }
}

// ---------------------------------------------------------------------------
// Pass 4: sorted labels (analytic from class bases) + loss finalize.
// ---------------------------------------------------------------------------
__global__ void label_kernel(const u32* __restrict__ cbase,
                             const double* __restrict__ acc, int N,
                             float* __restrict__ out_label,
                             float* __restrict__ out_loss) {
    int t = blockIdx.x * blockDim.x + threadIdx.x;
    u32 b1 = cbase[1], b2 = cbase[2], b3 = cbase[3];
    int j = t * 4;
    if (j + 3 < N) {
        float4 r;
        u32 j0 = (u32)j;
        r.x = (float)((j0 >= b1) + (j0 >= b2) + (j0 >= b3));
        r.y = (float)((j0 + 1 >= b1) + (j0 + 1 >= b2) + (j0 + 1 >= b3));
        r.z = (float)((j0 + 2 >= b1) + (j0 + 2 >= b2) + (j0 + 2 >= b3));
        r.w = (float)((j0 + 3 >= b1) + (j0 + 3 >= b2) + (j0 + 3 >= b3));
        ((float4*)out_label)[t] = r;
    } else {
        for (int k = 0; k < 4; ++k) {
            int jj = j + k;
            if (jj < N) {
                u32 ju = (u32)jj;
                out_label[jj] = (float)((ju >= b1) + (ju >= b2) + (ju >= b3));
            }
        }
    }
    if (t == 0) *out_loss = (float)(*acc / (double)N);
}

// ---------------------------------------------------------------------------
extern "C" void kernel_launch(void* const* d_in, const int* in_sizes, int n_in,
                              void* d_out, int out_size, void* d_ws,
                              size_t ws_size, hipStream_t stream) {
    const float* data = (const float*)d_in[0];
    const int* labels = (const int*)d_in[1];
    int N = in_sizes[1];
    int nb = (N + CHUNK - 1) / CHUNK;

    u32* hist = (u32*)d_ws;
    u32* boff = hist + (size_t)nb * 4;
    u32* cbase = boff + (size_t)nb * 4;
    double* acc =
        (double*)(((uintptr_t)(cbase + 4) + 15) & ~(uintptr_t)15);

    float* out = (float*)d_out;
    float* out_data = out;                       // N*4
    float* out_label = out + (size_t)N * 4;      // N
    float* out_loss = out + (size_t)N * 5;       // 1

    hist_kernel<<<nb, BLOCK, 0, stream>>>(labels, N, hist);
    scan_kernel<<<1, BLOCK, 0, stream>>>(hist, boff, cbase, acc, nb);
    scatter_kernel<<<nb, BLOCK, 0, stream>>>((const float4*)data, labels, N,
                                             boff, (float4*)out_data, acc);
    int lb = (N + 4 * BLOCK - 1) / (4 * BLOCK);
    label_kernel<<<lb, BLOCK, 0, stream>>>(cbase, acc, N, out_label, out_loss);
}

// Round 2
// 343.886 us; speedup vs baseline: 1.0071x; 1.0071x over previous
//
#include <hip/hip_runtime.h>
#include <math.h>
#include <stdint.h>

typedef unsigned int u32;
typedef unsigned long long u64;

#define BLOCK 256
#define ITEMS 16
#define CHUNK (BLOCK * ITEMS)  // 4096 elements per block

// ---------------------------------------------------------------------------
// Pass 1: per-block class histograms (4 classes), int4-vectorized.
// ---------------------------------------------------------------------------
__global__ void hist_kernel(const int* __restrict__ labels, int N,
                            u32* __restrict__ hist) {
    __shared__ u32 h[4];
    int tid = threadIdx.x;
    if (tid < 4) h[tid] = 0;
    __syncthreads();
    int base4 = blockIdx.x * (CHUNK / 4);
    const int4* l4 = (const int4*)labels;
    u32 c0 = 0, c1 = 0, c2 = 0, c3 = 0;
#pragma unroll
    for (int j = 0; j < ITEMS / 4; ++j) {
        int i4 = base4 + j * BLOCK + tid;
        if (4 * i4 + 3 < N) {
            int4 v = l4[i4];
            c0 += (v.x == 0) + (v.y == 0) + (v.z == 0) + (v.w == 0);
            c1 += (v.x == 1) + (v.y == 1) + (v.z == 1) + (v.w == 1);
            c2 += (v.x == 2) + (v.y == 2) + (v.z == 2) + (v.w == 2);
            c3 += (v.x == 3) + (v.y == 3) + (v.z == 3) + (v.w == 3);
        } else {
#pragma unroll
            for (int k = 0; k < 4; ++k) {
                int e = 4 * i4 + k;
                if (e < N) {
                    int l = labels[e];
                    c0 += (l == 0); c1 += (l == 1);
                    c2 += (l == 2); c3 += (l == 3);
                }
            }
        }
    }
    atomicAdd(&h[0], c0);
    atomicAdd(&h[1], c1);
    atomicAdd(&h[2], c2);
    atomicAdd(&h[3], c3);
    __syncthreads();
    if (tid < 4) hist[blockIdx.x * 4 + tid] = h[tid];
}

// ---------------------------------------------------------------------------
// Pass 2 (single block): scan block histograms -> per-block scatter bases
// (including class base), class bases, zero loss accumulator.
// ---------------------------------------------------------------------------
__global__ void scan_kernel(const u32* __restrict__ hist,
                            u32* __restrict__ boff,
                            u32* __restrict__ cbase,
                            double* __restrict__ acc,
                            int nb) {
    __shared__ uint4 s[BLOCK];
    __shared__ u32 sb[4];
    int t = threadIdx.x;
    int m = (nb + BLOCK - 1) / BLOCK;
    int b0 = t * m;
    int b1 = min(b0 + m, nb);
    uint4 loc = make_uint4(0, 0, 0, 0);
    for (int b = b0; b < b1; ++b) {
        loc.x += hist[b * 4 + 0];
        loc.y += hist[b * 4 + 1];
        loc.z += hist[b * 4 + 2];
        loc.w += hist[b * 4 + 3];
    }
    s[t] = loc;
    __syncthreads();
    for (int off = 1; off < BLOCK; off <<= 1) {
        uint4 v = make_uint4(0, 0, 0, 0);
        if (t >= off) v = s[t - off];
        __syncthreads();
        s[t].x += v.x; s[t].y += v.y; s[t].z += v.z; s[t].w += v.w;
        __syncthreads();
    }
    uint4 inc = s[t];
    uint4 tot = s[BLOCK - 1];
    if (t == 0) {
        sb[0] = 0;
        sb[1] = tot.x;
        sb[2] = tot.x + tot.y;
        sb[3] = tot.x + tot.y + tot.z;
        cbase[0] = sb[0]; cbase[1] = sb[1]; cbase[2] = sb[2]; cbase[3] = sb[3];
        *acc = 0.0;
    }
    __syncthreads();
    uint4 run;
    run.x = inc.x - loc.x + sb[0];
    run.y = inc.y - loc.y + sb[1];
    run.z = inc.z - loc.z + sb[2];
    run.w = inc.w - loc.w + sb[3];
    for (int b = b0; b < b1; ++b) {
        boff[b * 4 + 0] = run.x;
        boff[b * 4 + 1] = run.y;
        boff[b * 4 + 2] = run.z;
        boff[b * 4 + 3] = run.w;
        run.x += hist[b * 4 + 0];
        run.y += hist[b * 4 + 1];
        run.z += hist[b * 4 + 2];
        run.w += hist[b * 4 + 3];
    }
}

// ---------------------------------------------------------------------------
// Pass 3: stable rank + margin adjust + scatter + loss. Only 2 barriers:
// phase A (ballot counts -> LDS), scan (1 wave per class over 64 entries),
// phase B (free-running, fully pipelined loads/stores).
// ---------------------------------------------------------------------------
__global__ void __launch_bounds__(BLOCK)
scatter_kernel(const float4* __restrict__ data,
               const int* __restrict__ labels, int N,
               const u32* __restrict__ boff,
               float4* __restrict__ out_data,
               double* __restrict__ acc) {
    __shared__ u32 s_pre[ITEMS][4][4];  // [iter][wave][class]: count -> excl prefix
    __shared__ u32 s_b[4];
    __shared__ double s_w[4];
    int tid = threadIdx.x;
    int lane = tid & 63;
    int wave = tid >> 6;
    int base = blockIdx.x * CHUNK;

    // Phase A: ballot per-iteration wave counts (no barriers needed).
    u32 packed = 0, vmask = 0;
#pragma unroll
    for (int j = 0; j < ITEMS; ++j) {
        int idx = base + j * BLOCK + tid;
        bool valid = idx < N;
        int l = valid ? labels[idx] : 0;
        packed |= (u32)l << (2 * j);
        vmask |= (valid ? 1u : 0u) << j;
        u64 m0 = __ballot(valid && l == 0);
        u64 m1 = __ballot(valid && l == 1);
        u64 m2 = __ballot(valid && l == 2);
        u64 m3 = __ballot(valid && l == 3);
        if (lane == 0) {
            s_pre[j][wave][0] = (u32)__popcll(m0);
            s_pre[j][wave][1] = (u32)__popcll(m1);
            s_pre[j][wave][2] = (u32)__popcll(m2);
            s_pre[j][wave][3] = (u32)__popcll(m3);
        }
    }
    if (tid < 4) s_b[tid] = boff[blockIdx.x * 4 + tid];
    __syncthreads();

    // Scan: wave w owns class w; 64 entries in (j, wave) order.
    {
        int c = wave;
        int e = lane;
        u32 x = s_pre[e >> 2][e & 3][c];
        u32 orig = x;
#pragma unroll
        for (int off = 1; off < 64; off <<= 1) {
            u32 v = (u32)__shfl_up((int)x, off, 64);
            if (lane >= off) x += v;
        }
        s_pre[e >> 2][e & 3][c] = x - orig;  // exclusive prefix within block
    }
    __syncthreads();

    // Phase B: rank, adjust, scatter, loss — no barriers, deep pipelining.
    u64 ltm = (1ULL << lane) - 1ULL;
    float loss = 0.f;
    const float INV_M = 0.249999375f;  // 1/4.00001
#pragma unroll
    for (int j = 0; j < ITEMS; ++j) {
        bool valid = (vmask >> j) & 1;
        int l = (packed >> (2 * j)) & 3;
        u64 m0 = __ballot(valid && l == 0);
        u64 m1 = __ballot(valid && l == 1);
        u64 m2 = __ballot(valid && l == 2);
        u64 m3 = __ballot(valid && l == 3);
        if (valid) {
            u64 mm = (l == 0) ? m0 : (l == 1) ? m1 : (l == 2) ? m2 : m3;
            u32 pre = (u32)__popcll(mm & ltm);
            u32 dst = s_b[l] + s_pre[j][wave][l] + pre;
            int idx = base + j * BLOCK + tid;
            float4 r = data[idx];
            float v = (l == 0) ? r.x : (l == 1) ? r.y : (l == 2) ? r.z : r.w;
            float adj = (v > 0.f) ? (v * INV_M - 0.5f) : (v * 4.00001f - 0.5f);
            if (l == 0) r.x = adj;
            else if (l == 1) r.y = adj;
            else if (l == 2) r.z = adj;
            else r.w = adj;
            out_data[dst] = r;
            float mx = fmaxf(fmaxf(r.x, r.y), fmaxf(r.z, r.w));
            float se = __expf(r.x - mx) + __expf(r.y - mx) +
                       __expf(r.z - mx) + __expf(r.w - mx);
            loss += (mx + __logf(se)) - adj;  // -log p_true
        }
    }

    // Block-reduce loss in double, one atomic per block.
    double d = (double)loss;
#pragma unroll
    for (int off = 32; off > 0; off >>= 1) d += __shfl_down(d, off, 64);
    if (lane == 0) s_w[wave] = d;
    __syncthreads();
    if (tid == 0) atomicAdd(acc, s_w[0] + s_w[1] + s_w[2] + s_w[3]);
}

// ---------------------------------------------------------------------------
// Pass 4: sorted labels (analytic from class bases) + loss finalize.
// ---------------------------------------------------------------------------
__global__ void label_kernel(const u32* __restrict__ cbase,
                             const double* __restrict__ acc, int N,
                             float* __restrict__ out_label,
                             float* __restrict__ out_loss) {
    int t = blockIdx.x * blockDim.x + threadIdx.x;
    u32 b1 = cbase[1], b2 = cbase[2], b3 = cbase[3];
    int j = t * 4;
    if (j + 3 < N) {
        float4 r;
        u32 j0 = (u32)j;
        r.x = (float)((j0 >= b1) + (j0 >= b2) + (j0 >= b3));
        r.y = (float)((j0 + 1 >= b1) + (j0 + 1 >= b2) + (j0 + 1 >= b3));
        r.z = (float)((j0 + 2 >= b1) + (j0 + 2 >= b2) + (j0 + 2 >= b3));
        r.w = (float)((j0 + 3 >= b1) + (j0 + 3 >= b2) + (j0 + 3 >= b3));
        ((float4*)out_label)[t] = r;
    } else {
        for (int k = 0; k < 4; ++k) {
            int jj = j + k;
            if (jj < N) {
                u32 ju = (u32)jj;
                out_label[jj] = (float)((ju >= b1) + (ju >= b2) + (ju >= b3));
            }
        }
    }
    if (t == 0) *out_loss = (float)(*acc / (double)N);
}

// ---------------------------------------------------------------------------
extern "C" void kernel_launch(void* const* d_in, const int* in_sizes, int n_in,
                              void* d_out, int out_size, void* d_ws,
                              size_t ws_size, hipStream_t stream) {
    const float* data = (const float*)d_in[0];
    const int* labels = (const int*)d_in[1];
    int N = in_sizes[1];
    int nb = (N + CHUNK - 1) / CHUNK;

    u32* hist = (u32*)d_ws;
    u32* boff = hist + (size_t)nb * 4;
    u32* cbase = boff + (size_t)nb * 4;
    double* acc =
        (double*)(((uintptr_t)(cbase + 4) + 15) & ~(uintptr_t)15);

    float* out = (float*)d_out;
    float* out_data = out;                   // N*4
    float* out_label = out + (size_t)N * 4;  // N
    float* out_loss = out + (size_t)N * 5;   // 1

    hist_kernel<<<nb, BLOCK, 0, stream>>>(labels, N, hist);
    scan_kernel<<<1, BLOCK, 0, stream>>>(hist, boff, cbase, acc, nb);
    scatter_kernel<<<nb, BLOCK, 0, stream>>>((const float4*)data, labels, N,
                                             boff, (float4*)out_data, acc);
    int lb = (N + 4 * BLOCK - 1) / (4 * BLOCK);
    label_kernel<<<lb, BLOCK, 0, stream>>>(cbase, acc, N, out_label, out_loss);
}